// Round 4
// baseline (1213.529 us; speedup 1.0000x reference)
//
#include <hip/hip_runtime.h>

#define N_POINTS 8192
#define K_CENTERS 128
#define IFD 64
#define L1D 64
#define L2D 64
#define L3D 128
#define QS 4096  // max points per ball (observed max ~1.7K for N(0,1) coords)

typedef float vf16 __attribute__((ext_vector_type(16)));

#define LD4(p) (*(const float4*)(p))
// Param names must not collide with .x/.y/.z/.w member tokens.
#define FMA4(D_, O_, W_, V_)                       \
  D_[(O_) + 0] = fmaf(V_, (W_).x, D_[(O_) + 0]);   \
  D_[(O_) + 1] = fmaf(V_, (W_).y, D_[(O_) + 1]);   \
  D_[(O_) + 2] = fmaf(V_, (W_).z, D_[(O_) + 2]);   \
  D_[(O_) + 3] = fmaf(V_, (W_).w, D_[(O_) + 3]);

#define FMA16ROW(ACC_, PW_, HV_)                                    \
  {                                                                 \
    const float4 wa_ = LD4(PW_);                                    \
    const float4 wb_ = LD4((PW_) + 4);                              \
    const float4 wc_ = LD4((PW_) + 8);                              \
    const float4 wd_ = LD4((PW_) + 12);                             \
    FMA4(ACC_, 0, wa_, HV_)                                         \
    FMA4(ACC_, 4, wb_, HV_)                                         \
    FMA4(ACC_, 8, wc_, HV_)                                         \
    FMA4(ACC_, 12, wd_, HV_)                                        \
  }

#define SET16(ACC_, PB_)                                            \
  {                                                                 \
    const float4 a_ = LD4(PB_);                                     \
    const float4 b_ = LD4((PB_) + 4);                               \
    const float4 c_ = LD4((PB_) + 8);                               \
    const float4 d_ = LD4((PB_) + 12);                              \
    ACC_[0] = a_.x; ACC_[1] = a_.y; ACC_[2] = a_.z; ACC_[3] = a_.w; \
    ACC_[4] = b_.x; ACC_[5] = b_.y; ACC_[6] = b_.z; ACC_[7] = b_.w; \
    ACC_[8] = c_.x; ACC_[9] = c_.y; ACC_[10] = c_.z; ACC_[11] = c_.w; \
    ACC_[12] = d_.x; ACC_[13] = d_.y; ACC_[14] = d_.z; ACC_[15] = d_.w; \
  }

// ---------------------------------------------------------------------------
// DPP u64-max step: partner = DPP-permuted (hi,lo); keep the larger key.
// ---------------------------------------------------------------------------
template <int CTRL, int RMASK>
__device__ __forceinline__ void dpp_max_u64(unsigned& hi, unsigned& lo) {
  unsigned h2 = (unsigned)__builtin_amdgcn_update_dpp(
      (int)hi, (int)hi, CTRL, RMASK, 0xF, false);
  unsigned l2 = (unsigned)__builtin_amdgcn_update_dpp(
      (int)lo, (int)lo, CTRL, RMASK, 0xF, false);
  unsigned long long a = ((unsigned long long)hi << 32) | lo;
  unsigned long long b = ((unsigned long long)h2 << 32) | l2;
  if (b > a) { hi = h2; lo = l2; }
}

// ---------------------------------------------------------------------------
// Kernel A: block 0 = FPS (unchanged, ~structural floor); blocks 1..128 =
// GT precompute in natural [n][64] layout + counts/out_feat zeroing.
// ---------------------------------------------------------------------------
#define FPS_T 512
#define FPS_P (N_POINTS / FPS_T)  // 16

#define SMEM_BYTES (98304 + 128)  // fps: 96 KB coords + wmax; GT: 16 KB W

__global__ __launch_bounds__(FPS_T) void fps_gt_kernel(
    const float* __restrict__ coords, float* __restrict__ out_centers,
    const float* __restrict__ features, const float* __restrict__ W1,
    const float* __restrict__ b1, float* __restrict__ GT,
    int* __restrict__ counts, float* __restrict__ out_feat) {
  __shared__ __align__(16) char smem[SMEM_BYTES];
  const int tid = threadIdx.x;

  if (blockIdx.x != 0) {
    // ---- GT precompute (feature half of L1), natural [n][64] layout ----
    float* w = (float*)smem;  // 16 KB
    const int bk = blockIdx.x - 1;
    if (bk == 0 && tid < K_CENTERS) counts[tid] = 0;
    if (bk == 1) {
#pragma unroll 1
      for (int s = tid; s < K_CENTERS * L3D; s += FPS_T) out_feat[s] = 0.0f;
    }
    const int n0 = bk * 64;
    for (int s = tid; s < IFD * L1D; s += FPS_T) w[s] = W1[3 * L1D + s];
    __syncthreads();
    const int j = tid & 63;
    const int nl = tid >> 6;  // 0..7 (uniform per wave -> frow is s_load)
    const float bj = b1[j];
#pragma unroll 1
    for (int itn = 0; itn < 8; itn++) {
      const int nn = nl + itn * 8;  // 0..63
      const float* __restrict__ frow = features + (size_t)(n0 + nn) * IFD;
      float acc = bj;
#pragma unroll 16
      for (int i = 0; i < IFD; i++) acc = fmaf(frow[i], w[i * 64 + j], acc);
      GT[(size_t)(n0 + nn) * 64 + j] = acc;  // coalesced: lane = channel j
    }
    return;
  }

  // ---- FPS (block 0, single CU) — unchanged from round 9 ----
  float* clds = (float*)smem;  // [8192][3] mirror of coords
  unsigned long long* wmax = (unsigned long long*)(smem + 98304);  // [2][8]
  const int lane = tid & 63;
  const int wid = tid >> 6;

  {
    const float4* __restrict__ src = (const float4*)coords;
    float4* dst = (float4*)smem;
#pragma unroll
    for (int i = 0; i < 12; i++) dst[tid + i * FPS_T] = src[tid + i * FPS_T];
  }

  float px[FPS_P], py[FPS_P], pz[FPS_P], mind[FPS_P];
#pragma unroll
  for (int i = 0; i < FPS_P; i++) {
    int n = tid + i * FPS_T;
    px[i] = coords[3 * n];
    py[i] = coords[3 * n + 1];
    pz[i] = coords[3 * n + 2];
    mind[i] = 1e10f;
  }

  float cx = coords[0], cy = coords[1], cz = coords[2];
  if (tid == 0) {
    out_centers[0] = cx; out_centers[1] = cy; out_centers[2] = cz;
  }
  __syncthreads();  // LDS coords mirror complete

  for (int it = 1; it < K_CENTERS; it++) {
#pragma unroll
    for (int i = 0; i < FPS_P; i++) {
      float dx = px[i] - cx, dy = py[i] - cy, dz = pz[i] - cz;
      float d2 = dx * dx + dy * dy + dz * dz;  // exact expr of passing rounds
      mind[i] = fminf(mind[i], d2);
    }
    // value: depth-4 fmax tree
    float t8[8];
#pragma unroll
    for (int i = 0; i < 8; i++) t8[i] = fmaxf(mind[i], mind[i + 8]);
#pragma unroll
    for (int i = 0; i < 4; i++) t8[i] = fmaxf(t8[i], t8[i + 4]);
    const float bm = fmaxf(fmaxf(t8[0], t8[1]), fmaxf(t8[2], t8[3]));
    // index: 16 parallel cndmask + depth-4 min tree (first match = min idx)
    int cand[FPS_P];
#pragma unroll
    for (int i = 0; i < FPS_P; i++)
      cand[i] = (mind[i] == bm) ? (tid + i * FPS_T) : 0x7FFFFFFF;
#pragma unroll
    for (int s = 8; s > 0; s >>= 1)
#pragma unroll
      for (int i = 0; i < s; i++) cand[i] = min(cand[i], cand[i + s]);

    unsigned hi = __float_as_uint(bm);                  // bm >= 0
    unsigned lo = (unsigned)(N_POINTS - 1 - cand[0]);   // max -> min index
    dpp_max_u64<0xB1, 0xF>(hi, lo);   // quad_perm [1,0,3,2]  (xor 1)
    dpp_max_u64<0x4E, 0xF>(hi, lo);   // quad_perm [2,3,0,1]  (xor 2)
    dpp_max_u64<0x141, 0xF>(hi, lo);  // row_half_mirror      (xor 7)
    dpp_max_u64<0x140, 0xF>(hi, lo);  // row_mirror           (xor 15)
    dpp_max_u64<0x142, 0xA>(hi, lo);  // bcast15 -> rows 1,3
    dpp_max_u64<0x143, 0xC>(hi, lo);  // bcast31 -> rows 2,3; lane63 = max
    const int buf = it & 1;
    if (lane == 63)
      wmax[(buf << 3) + wid] = ((unsigned long long)hi << 32) | lo;
    __syncthreads();  // double-buffered: one barrier per iteration is safe

    const unsigned long long* __restrict__ wb = wmax + (buf << 3);
    unsigned long long a0 = wb[0], a1 = wb[1], a2 = wb[2], a3 = wb[3];
    unsigned long long a4 = wb[4], a5 = wb[5], a6 = wb[6], a7 = wb[7];
    a0 = a0 > a4 ? a0 : a4;
    a1 = a1 > a5 ? a1 : a5;
    a2 = a2 > a6 ? a2 : a6;
    a3 = a3 > a7 ? a3 : a7;
    a0 = a0 > a2 ? a0 : a2;
    a1 = a1 > a3 ? a1 : a3;
    a0 = a0 > a1 ? a0 : a1;
    const int widx = N_POINTS - 1 - (int)(a0 & 0xFFFFFFFFull);
    cx = clds[widx * 3];          // broadcast ds_read, no barrier needed
    cy = clds[widx * 3 + 1];
    cz = clds[widx * 3 + 2];
    if (tid == 0) {
      out_centers[3 * it] = cx;
      out_centers[3 * it + 1] = cy;
      out_centers[3 * it + 2] = cz;
    }
  }
}

// ---------------------------------------------------------------------------
// Kernel B: ball query, 512 blocks, global atomic slot alloc. Unchanged.
// ---------------------------------------------------------------------------
#define PREP_PARTS 4
#define PREP_PTS (N_POINTS / PREP_PARTS)  // 2048

__global__ __launch_bounds__(256) void prep_kernel(
    const float* __restrict__ coords, const float* __restrict__ centers,
    int* __restrict__ counts, int* __restrict__ Q) {
  const int tid = threadIdx.x;
  const int k = blockIdx.x >> 2;
  const int part = blockIdx.x & 3;
  const float cx = centers[3 * k], cy = centers[3 * k + 1],
              cz = centers[3 * k + 2];
  const int nbase = part * PREP_PTS;
#pragma unroll
  for (int s = 0; s < PREP_PTS / 256; s++) {
    const int n = nbase + s * 256 + tid;
    float dx = coords[3 * n] - cx;
    float dy = coords[3 * n + 1] - cy;
    float dz = coords[3 * n + 2] - cz;
    float d2 = dx * dx + dy * dy + dz * dz;
    if (sqrtf(d2) < 1.0f) {  // match reference: norm(rel) < RADIUS
      int p = atomicAdd(&counts[k], 1);  // wave-coalesced by compiler
      if (p < QS) Q[(k << 12) + p] = n;  // consecutive p -> coalesced store
    }
  }
}

// ---------------------------------------------------------------------------
// Kernel C (round-11): WEIGHTS IN LDS. Round-10 post-mortem: ~3K wave-
// uniform weight loads per chunk went through scalar s_loads; W3 (32 KB)
// thrashes the 16 KB scalar K$ -> ~100-cyc L2 round trips, ~95% stall
// (VALUBusy 5.6%). Now W1c/W2/W3/b2/b3 are staged once per block into LDS
// (49.5 KB -> 3 blocks/CU, 12 waves/CU) and read as same-address ds_read
// broadcasts (conflict-free, deeply pipelined). hbuf is GONE: h2 stays in
// a2[64] registers; L3 keeps jg as a runtime loop (only LDS addresses
// depend on it) and fully unrolls i so a2[i] is always a compile-time
// index (no scratch). Accumulation order identical -> bit-identical.
// ---------------------------------------------------------------------------
#define MLP_BLOCKS 512

__global__ __launch_bounds__(256) void mlp_kernel(
    const float* __restrict__ coords, const float* __restrict__ GT,
    const float* __restrict__ W1, const float* __restrict__ W2,
    const float* __restrict__ b2, const float* __restrict__ W3,
    const float* __restrict__ b3, const float* __restrict__ centers,
    const int* __restrict__ counts, const int* __restrict__ Q,
    float* __restrict__ out_feat) {
  __shared__ __align__(16) float w1s[3 * 64];        // 768 B (coords rows)
  __shared__ __align__(16) float w2s[64 * 64];       // 16 KB
  __shared__ __align__(16) float w3s[64 * 128];      // 32 KB
  __shared__ __align__(16) float b2s[64];
  __shared__ __align__(16) float b3s[128];
  const int tid = threadIdx.x;
  const int lane = tid & 63;

  for (int s = tid; s < 64 * 64; s += 256) w2s[s] = W2[s];
  for (int s = tid; s < 64 * 128; s += 256) w3s[s] = W3[s];
  if (tid < 192) w1s[tid] = W1[tid];
  if (tid < 64) b2s[tid] = b2[tid];
  if (tid >= 64 && tid < 192) b3s[tid - 64] = b3[tid - 64];
  __syncthreads();

  const int gwave = (blockIdx.x * 256 + tid) >> 6;
  const int nwaves = (gridDim.x * 256) >> 6;

  // per-wave chunk prefix over centers: P_k = ceil(min(counts[k],QS)/64)
  int c0 = counts[lane];      if (c0 > QS) c0 = QS;
  int c1 = counts[64 + lane]; if (c1 > QS) c1 = QS;
  int s0 = (c0 + 63) >> 6;
  int s1 = (c1 + 63) >> 6;
#pragma unroll
  for (int off = 1; off < 64; off <<= 1) {
    int t0 = __shfl_up(s0, off, 64);
    int t1 = __shfl_up(s1, off, 64);
    if (lane >= off) { s0 += t0; s1 += t1; }
  }
  s1 += __shfl(s0, 63, 64);
  const int C = __shfl(s1, 63, 64);  // total chunks
  const int p1 = s0;                 // prefix[lane+1]
  const int p65 = s1;                // prefix[lane+65]

  for (int c = gwave; c < C; c += nwaves) {
    int k = __popcll(__ballot(p1 <= c)) + __popcll(__ballot(p65 <= c));
    k = __builtin_amdgcn_readfirstlane(k);
    int pk = 0;
    if (k > 0)
      pk = (k <= 64) ? __shfl(s0, k - 1, 64) : __shfl(s1, k - 65, 64);
    int Mk = counts[k];
    if (Mk > QS) Mk = QS;
    int m = (c - pk) * 64 + lane;
    if (m >= Mk) m = Mk - 1;  // pad with a real point; duplicate ok for max
    const int n = Q[(k << 12) + m];

    const float cx = centers[3 * k], cy = centers[3 * k + 1],
                cz = centers[3 * k + 2];
    const float dx = coords[3 * n] - cx;
    const float dy = coords[3 * n + 1] - cy;
    const float dz = coords[3 * n + 2] - cz;

    // ---- single-pass L1+L2: 64 register accumulators, static indices ----
    float a2[64];
#pragma unroll
    for (int j4 = 0; j4 < 16; j4++) {
      const float4 bv = LD4(b2s + j4 * 4);
      a2[j4 * 4 + 0] = bv.x; a2[j4 * 4 + 1] = bv.y;
      a2[j4 * 4 + 2] = bv.z; a2[j4 * 4 + 3] = bv.w;
    }
    const float* __restrict__ gr = GT + (size_t)n * 64;
#pragma unroll 4
    for (int i = 0; i < 64; i += 4) {
      const float4 g = LD4(gr + i);  // per-lane contiguous 16 B
      const float e0 = fmaxf(
          fmaf(dz, w1s[128 + i], fmaf(dy, w1s[64 + i], fmaf(dx, w1s[i], g.x))),
          0.0f);
      const float e1 = fmaxf(
          fmaf(dz, w1s[129 + i],
               fmaf(dy, w1s[65 + i], fmaf(dx, w1s[i + 1], g.y))),
          0.0f);
      const float e2 = fmaxf(
          fmaf(dz, w1s[130 + i],
               fmaf(dy, w1s[66 + i], fmaf(dx, w1s[i + 2], g.z))),
          0.0f);
      const float e3 = fmaxf(
          fmaf(dz, w1s[131 + i],
               fmaf(dy, w1s[67 + i], fmaf(dx, w1s[i + 3], g.w))),
          0.0f);
      const float* __restrict__ w2r = w2s + i * 64;  // uniform -> broadcast
#pragma unroll
      for (int j4 = 0; j4 < 16; j4++) {
        const float4 wa = LD4(w2r + j4 * 4);
        const float4 wb = LD4(w2r + 64 + j4 * 4);
        const float4 wc = LD4(w2r + 128 + j4 * 4);
        const float4 wd = LD4(w2r + 192 + j4 * 4);
        // per-j order e0,e1,e2,e3 == round-6 FMA16ROW sequence
        a2[j4 * 4 + 0] = fmaf(e0, wa.x, a2[j4 * 4 + 0]);
        a2[j4 * 4 + 1] = fmaf(e0, wa.y, a2[j4 * 4 + 1]);
        a2[j4 * 4 + 2] = fmaf(e0, wa.z, a2[j4 * 4 + 2]);
        a2[j4 * 4 + 3] = fmaf(e0, wa.w, a2[j4 * 4 + 3]);
        a2[j4 * 4 + 0] = fmaf(e1, wb.x, a2[j4 * 4 + 0]);
        a2[j4 * 4 + 1] = fmaf(e1, wb.y, a2[j4 * 4 + 1]);
        a2[j4 * 4 + 2] = fmaf(e1, wb.z, a2[j4 * 4 + 2]);
        a2[j4 * 4 + 3] = fmaf(e1, wb.w, a2[j4 * 4 + 3]);
        a2[j4 * 4 + 0] = fmaf(e2, wc.x, a2[j4 * 4 + 0]);
        a2[j4 * 4 + 1] = fmaf(e2, wc.y, a2[j4 * 4 + 1]);
        a2[j4 * 4 + 2] = fmaf(e2, wc.z, a2[j4 * 4 + 2]);
        a2[j4 * 4 + 3] = fmaf(e2, wc.w, a2[j4 * 4 + 3]);
        a2[j4 * 4 + 0] = fmaf(e3, wd.x, a2[j4 * 4 + 0]);
        a2[j4 * 4 + 1] = fmaf(e3, wd.y, a2[j4 * 4 + 1]);
        a2[j4 * 4 + 2] = fmaf(e3, wd.z, a2[j4 * 4 + 2]);
        a2[j4 * 4 + 3] = fmaf(e3, wd.w, a2[j4 * 4 + 3]);
      }
    }
    // relu in place (same values as the old LDS round-trip)
#pragma unroll
    for (int j = 0; j < 64; j++) a2[j] = fmaxf(a2[j], 0.0f);

    // ---- L3: jg runtime (LDS addrs only), i FULLY unrolled (a2 static) ---
#pragma unroll 1
    for (int jg = 0; jg < 8; jg++) {
      vf16 acc;
      SET16(acc, b3s + jg * 16)
      const float* __restrict__ w3g = w3s + jg * 16;  // uniform -> broadcast
#pragma unroll
      for (int i = 0; i < 64; i += 4) {
        const float e0 = a2[i + 0];   // i compile-time: stays in VGPRs
        const float e1 = a2[i + 1];
        const float e2 = a2[i + 2];
        const float e3 = a2[i + 3];
        const float* __restrict__ w3r = w3g + i * L3D;
        FMA16ROW(acc, w3r, e0)
        FMA16ROW(acc, w3r + 128, e1)
        FMA16ROW(acc, w3r + 256, e2)
        FMA16ROW(acc, w3r + 384, e3)
      }
#pragma unroll
      for (int t = 0; t < 16; t++) {
        float v = fmaxf(acc[t], 0.0f);
#pragma unroll
        for (int off = 32; off >= 1; off >>= 1)
          v = fmaxf(v, __shfl_xor(v, off, 64));
        if (lane == 0)
          atomicMax((unsigned int*)&out_feat[k * L3D + jg * 16 + t],
                    __float_as_uint(v));
      }
    }
  }
}

// ---------------------------------------------------------------------------
extern "C" void kernel_launch(void* const* d_in, const int* in_sizes, int n_in,
                              void* d_out, int out_size, void* d_ws,
                              size_t ws_size, hipStream_t stream) {
  const float* coords = (const float*)d_in[0];    // [8192,3]
  const float* features = (const float*)d_in[1];  // [8192,64]
  const float* W1 = (const float*)d_in[2];        // [67,64]
  const float* b1 = (const float*)d_in[3];        // [64]
  const float* W2 = (const float*)d_in[4];        // [64,64]
  const float* b2 = (const float*)d_in[5];        // [64]
  const float* W3 = (const float*)d_in[6];        // [64,128]
  const float* b3 = (const float*)d_in[7];        // [128]

  float* out = (float*)d_out;
  float* centers = out;                   // [128*3]
  float* out_feat = out + K_CENTERS * 3;  // [128*128]

  char* ws = (char*)d_ws;
  float* GT = (float*)ws;                            // 2 MB, [8192][64]
  int* Q = (int*)(ws + (size_t)N_POINTS * L1D * 4);  // 2 MB
  int* counts = (int*)(ws + 4 * 1024 * 1024);        // 512 B

  fps_gt_kernel<<<1 + K_CENTERS, FPS_T, 0, stream>>>(
      coords, centers, features, W1, b1, GT, counts, out_feat);
  prep_kernel<<<PREP_PARTS * K_CENTERS, 256, 0, stream>>>(coords, centers,
                                                          counts, Q);
  mlp_kernel<<<MLP_BLOCKS, 256, 0, stream>>>(coords, GT, W1, W2, b2, W3, b3,
                                             centers, counts, Q, out_feat);
}

// Round 5
// 295.143 us; speedup vs baseline: 4.1117x; 4.1117x over previous
//
#include <hip/hip_runtime.h>

#define N_POINTS 8192
#define K_CENTERS 128
#define IFD 64
#define L1D 64
#define L2D 64
#define L3D 128
#define QS 4096  // max points per ball (observed max ~1.7K for N(0,1) coords)

typedef float vf16 __attribute__((ext_vector_type(16)));

#define LD4(p) (*(const float4*)(p))
// Param names must not collide with .x/.y/.z/.w member tokens.
#define FMA4(D_, O_, W_, V_)                       \
  D_[(O_) + 0] = fmaf(V_, (W_).x, D_[(O_) + 0]);   \
  D_[(O_) + 1] = fmaf(V_, (W_).y, D_[(O_) + 1]);   \
  D_[(O_) + 2] = fmaf(V_, (W_).z, D_[(O_) + 2]);   \
  D_[(O_) + 3] = fmaf(V_, (W_).w, D_[(O_) + 3]);

#define FMA16ROW(ACC_, PW_, HV_)                                    \
  {                                                                 \
    const float4 wa_ = LD4(PW_);                                    \
    const float4 wb_ = LD4((PW_) + 4);                              \
    const float4 wc_ = LD4((PW_) + 8);                              \
    const float4 wd_ = LD4((PW_) + 12);                             \
    FMA4(ACC_, 0, wa_, HV_)                                         \
    FMA4(ACC_, 4, wb_, HV_)                                         \
    FMA4(ACC_, 8, wc_, HV_)                                         \
    FMA4(ACC_, 12, wd_, HV_)                                        \
  }

#define SET16(ACC_, PB_)                                            \
  {                                                                 \
    const float4 a_ = LD4(PB_);                                     \
    const float4 b_ = LD4((PB_) + 4);                               \
    const float4 c_ = LD4((PB_) + 8);                               \
    const float4 d_ = LD4((PB_) + 12);                              \
    ACC_[0] = a_.x; ACC_[1] = a_.y; ACC_[2] = a_.z; ACC_[3] = a_.w; \
    ACC_[4] = b_.x; ACC_[5] = b_.y; ACC_[6] = b_.z; ACC_[7] = b_.w; \
    ACC_[8] = c_.x; ACC_[9] = c_.y; ACC_[10] = c_.z; ACC_[11] = c_.w; \
    ACC_[12] = d_.x; ACC_[13] = d_.y; ACC_[14] = d_.z; ACC_[15] = d_.w; \
  }

// ---------------------------------------------------------------------------
// DPP u64-max step: partner = DPP-permuted (hi,lo); keep the larger key.
// ---------------------------------------------------------------------------
template <int CTRL, int RMASK>
__device__ __forceinline__ void dpp_max_u64(unsigned& hi, unsigned& lo) {
  unsigned h2 = (unsigned)__builtin_amdgcn_update_dpp(
      (int)hi, (int)hi, CTRL, RMASK, 0xF, false);
  unsigned l2 = (unsigned)__builtin_amdgcn_update_dpp(
      (int)lo, (int)lo, CTRL, RMASK, 0xF, false);
  unsigned long long a = ((unsigned long long)hi << 32) | lo;
  unsigned long long b = ((unsigned long long)h2 << 32) | l2;
  if (b > a) { hi = h2; lo = l2; }
}

// ---------------------------------------------------------------------------
// Kernel A: block 0 = FPS (unchanged, ~structural floor); blocks 1..128 =
// GT precompute in natural [n][64] layout + counts/out_feat zeroing.
// ---------------------------------------------------------------------------
#define FPS_T 512
#define FPS_P (N_POINTS / FPS_T)  // 16

#define SMEM_BYTES (98304 + 128)  // fps: 96 KB coords + wmax; GT: 16 KB W

__global__ __launch_bounds__(FPS_T) void fps_gt_kernel(
    const float* __restrict__ coords, float* __restrict__ out_centers,
    const float* __restrict__ features, const float* __restrict__ W1,
    const float* __restrict__ b1, float* __restrict__ GT,
    int* __restrict__ counts, float* __restrict__ out_feat) {
  __shared__ __align__(16) char smem[SMEM_BYTES];
  const int tid = threadIdx.x;

  if (blockIdx.x != 0) {
    // ---- GT precompute (feature half of L1), natural [n][64] layout ----
    float* w = (float*)smem;  // 16 KB
    const int bk = blockIdx.x - 1;
    if (bk == 0 && tid < K_CENTERS) counts[tid] = 0;
    if (bk == 1) {
#pragma unroll 1
      for (int s = tid; s < K_CENTERS * L3D; s += FPS_T) out_feat[s] = 0.0f;
    }
    const int n0 = bk * 64;
    for (int s = tid; s < IFD * L1D; s += FPS_T) w[s] = W1[3 * L1D + s];
    __syncthreads();
    const int j = tid & 63;
    const int nl = tid >> 6;  // 0..7 (uniform per wave -> frow is s_load)
    const float bj = b1[j];
#pragma unroll 1
    for (int itn = 0; itn < 8; itn++) {
      const int nn = nl + itn * 8;  // 0..63
      const float* __restrict__ frow = features + (size_t)(n0 + nn) * IFD;
      float acc = bj;
#pragma unroll 16
      for (int i = 0; i < IFD; i++) acc = fmaf(frow[i], w[i * 64 + j], acc);
      GT[(size_t)(n0 + nn) * 64 + j] = acc;  // coalesced: lane = channel j
    }
    return;
  }

  // ---- FPS (block 0, single CU) — unchanged from round 9 ----
  float* clds = (float*)smem;  // [8192][3] mirror of coords
  unsigned long long* wmax = (unsigned long long*)(smem + 98304);  // [2][8]
  const int lane = tid & 63;
  const int wid = tid >> 6;

  {
    const float4* __restrict__ src = (const float4*)coords;
    float4* dst = (float4*)smem;
#pragma unroll
    for (int i = 0; i < 12; i++) dst[tid + i * FPS_T] = src[tid + i * FPS_T];
  }

  float px[FPS_P], py[FPS_P], pz[FPS_P], mind[FPS_P];
#pragma unroll
  for (int i = 0; i < FPS_P; i++) {
    int n = tid + i * FPS_T;
    px[i] = coords[3 * n];
    py[i] = coords[3 * n + 1];
    pz[i] = coords[3 * n + 2];
    mind[i] = 1e10f;
  }

  float cx = coords[0], cy = coords[1], cz = coords[2];
  if (tid == 0) {
    out_centers[0] = cx; out_centers[1] = cy; out_centers[2] = cz;
  }
  __syncthreads();  // LDS coords mirror complete

  for (int it = 1; it < K_CENTERS; it++) {
#pragma unroll
    for (int i = 0; i < FPS_P; i++) {
      float dx = px[i] - cx, dy = py[i] - cy, dz = pz[i] - cz;
      float d2 = dx * dx + dy * dy + dz * dz;  // exact expr of passing rounds
      mind[i] = fminf(mind[i], d2);
    }
    // value: depth-4 fmax tree
    float t8[8];
#pragma unroll
    for (int i = 0; i < 8; i++) t8[i] = fmaxf(mind[i], mind[i + 8]);
#pragma unroll
    for (int i = 0; i < 4; i++) t8[i] = fmaxf(t8[i], t8[i + 4]);
    const float bm = fmaxf(fmaxf(t8[0], t8[1]), fmaxf(t8[2], t8[3]));
    // index: 16 parallel cndmask + depth-4 min tree (first match = min idx)
    int cand[FPS_P];
#pragma unroll
    for (int i = 0; i < FPS_P; i++)
      cand[i] = (mind[i] == bm) ? (tid + i * FPS_T) : 0x7FFFFFFF;
#pragma unroll
    for (int s = 8; s > 0; s >>= 1)
#pragma unroll
      for (int i = 0; i < s; i++) cand[i] = min(cand[i], cand[i + s]);

    unsigned hi = __float_as_uint(bm);                  // bm >= 0
    unsigned lo = (unsigned)(N_POINTS - 1 - cand[0]);   // max -> min index
    dpp_max_u64<0xB1, 0xF>(hi, lo);   // quad_perm [1,0,3,2]  (xor 1)
    dpp_max_u64<0x4E, 0xF>(hi, lo);   // quad_perm [2,3,0,1]  (xor 2)
    dpp_max_u64<0x141, 0xF>(hi, lo);  // row_half_mirror      (xor 7)
    dpp_max_u64<0x140, 0xF>(hi, lo);  // row_mirror           (xor 15)
    dpp_max_u64<0x142, 0xA>(hi, lo);  // bcast15 -> rows 1,3
    dpp_max_u64<0x143, 0xC>(hi, lo);  // bcast31 -> rows 2,3; lane63 = max
    const int buf = it & 1;
    if (lane == 63)
      wmax[(buf << 3) + wid] = ((unsigned long long)hi << 32) | lo;
    __syncthreads();  // double-buffered: one barrier per iteration is safe

    const unsigned long long* __restrict__ wb = wmax + (buf << 3);
    unsigned long long a0 = wb[0], a1 = wb[1], a2 = wb[2], a3 = wb[3];
    unsigned long long a4 = wb[4], a5 = wb[5], a6 = wb[6], a7 = wb[7];
    a0 = a0 > a4 ? a0 : a4;
    a1 = a1 > a5 ? a1 : a5;
    a2 = a2 > a6 ? a2 : a6;
    a3 = a3 > a7 ? a3 : a7;
    a0 = a0 > a2 ? a0 : a2;
    a1 = a1 > a3 ? a1 : a3;
    a0 = a0 > a1 ? a0 : a1;
    const int widx = N_POINTS - 1 - (int)(a0 & 0xFFFFFFFFull);
    cx = clds[widx * 3];          // broadcast ds_read, no barrier needed
    cy = clds[widx * 3 + 1];
    cz = clds[widx * 3 + 2];
    if (tid == 0) {
      out_centers[3 * it] = cx;
      out_centers[3 * it + 1] = cy;
      out_centers[3 * it + 2] = cz;
    }
  }
}

// ---------------------------------------------------------------------------
// Kernel B: ball query, 512 blocks, global atomic slot alloc. Unchanged.
// ---------------------------------------------------------------------------
#define PREP_PARTS 4
#define PREP_PTS (N_POINTS / PREP_PARTS)  // 2048

__global__ __launch_bounds__(256) void prep_kernel(
    const float* __restrict__ coords, const float* __restrict__ centers,
    int* __restrict__ counts, int* __restrict__ Q) {
  const int tid = threadIdx.x;
  const int k = blockIdx.x >> 2;
  const int part = blockIdx.x & 3;
  const float cx = centers[3 * k], cy = centers[3 * k + 1],
              cz = centers[3 * k + 2];
  const int nbase = part * PREP_PTS;
#pragma unroll
  for (int s = 0; s < PREP_PTS / 256; s++) {
    const int n = nbase + s * 256 + tid;
    float dx = coords[3 * n] - cx;
    float dy = coords[3 * n + 1] - cy;
    float dz = coords[3 * n + 2] - cz;
    float d2 = dx * dx + dy * dy + dz * dz;
    if (sqrtf(d2) < 1.0f) {  // match reference: norm(rel) < RADIUS
      int p = atomicAdd(&counts[k], 1);  // wave-coalesced by compiler
      if (p < QS) Q[(k << 12) + p] = n;  // consecutive p -> coalesced store
    }
  }
}

// ---------------------------------------------------------------------------
// Kernel C (round-12): round-4 post-mortem — removing hbuf + full L3 unroll
// spilled a2[64] (VGPR 256, WRITE 472 MB of scratch). REVERT to the spill-
// free round-3 structure (h2 via 64 KB hbuf, VGPR~100) and change ONLY the
// weight path: W1c/W2/W3/b2/b3 staged ONCE per block into LDS, read as
// same-address broadcast ds_read_b128 (conflict-free, pipelined) instead
// of the scalar s_loads that thrashed the 16 KB K$ (round-3's 94% stall).
// LDS = 64 + 49.5 KB -> 1 block/CU; grid = 256 (one block per CU, weights
// staged once); waves grid-stride over chunks. Accumulation order is
// byte-identical to rounds 3/4 (both passed).
// ---------------------------------------------------------------------------
#define MLP_BLOCKS 256

__global__ __launch_bounds__(256) void mlp_kernel(
    const float* __restrict__ coords, const float* __restrict__ GT,
    const float* __restrict__ W1, const float* __restrict__ W2,
    const float* __restrict__ b2, const float* __restrict__ W3,
    const float* __restrict__ b3, const float* __restrict__ centers,
    const int* __restrict__ counts, const int* __restrict__ Q,
    float* __restrict__ out_feat) {
  __shared__ float hbuf[256 * 64];              // 64 KB: per-thread h2 row
  __shared__ __align__(16) float w1s[3 * 64];   // 768 B (coords rows of W1)
  __shared__ __align__(16) float w2s[64 * 64];  // 16 KB
  __shared__ __align__(16) float w3s[64 * 128]; // 32 KB
  __shared__ __align__(16) float b2s[64];
  __shared__ __align__(16) float b3s[128];
  const int tid = threadIdx.x;
  const int lane = tid & 63;
  float* __restrict__ hrow = hbuf + tid * 64;

  for (int s = tid; s < 64 * 64; s += 256) w2s[s] = W2[s];
  for (int s = tid; s < 64 * 128; s += 256) w3s[s] = W3[s];
  if (tid < 192) w1s[tid] = W1[tid];
  if (tid < 64) b2s[tid] = b2[tid];
  if (tid >= 64 && tid < 192) b3s[tid - 64] = b3[tid - 64];
  __syncthreads();

  const int gwave = (blockIdx.x * 256 + tid) >> 6;
  const int nwaves = (gridDim.x * 256) >> 6;

  // per-wave chunk prefix over centers: P_k = ceil(min(counts[k],QS)/64)
  int c0 = counts[lane];      if (c0 > QS) c0 = QS;
  int c1 = counts[64 + lane]; if (c1 > QS) c1 = QS;
  int s0 = (c0 + 63) >> 6;
  int s1 = (c1 + 63) >> 6;
#pragma unroll
  for (int off = 1; off < 64; off <<= 1) {
    int t0 = __shfl_up(s0, off, 64);
    int t1 = __shfl_up(s1, off, 64);
    if (lane >= off) { s0 += t0; s1 += t1; }
  }
  s1 += __shfl(s0, 63, 64);
  const int C = __shfl(s1, 63, 64);  // total chunks
  const int p1 = s0;                 // prefix[lane+1]
  const int p65 = s1;                // prefix[lane+65]

  for (int c = gwave; c < C; c += nwaves) {
    int k = __popcll(__ballot(p1 <= c)) + __popcll(__ballot(p65 <= c));
    k = __builtin_amdgcn_readfirstlane(k);
    int pk = 0;
    if (k > 0)
      pk = (k <= 64) ? __shfl(s0, k - 1, 64) : __shfl(s1, k - 65, 64);
    int Mk = counts[k];
    if (Mk > QS) Mk = QS;
    int m = (c - pk) * 64 + lane;
    if (m >= Mk) m = Mk - 1;  // pad with a real point; duplicate ok for max
    const int n = Q[(k << 12) + m];

    const float cx = centers[3 * k], cy = centers[3 * k + 1],
                cz = centers[3 * k + 2];
    const float dx = coords[3 * n] - cx;
    const float dy = coords[3 * n + 1] - cy;
    const float dz = coords[3 * n + 2] - cz;

    // ---- single-pass L1+L2: 64 register accumulators, static indices ----
    float a2[64];
#pragma unroll
    for (int j4 = 0; j4 < 16; j4++) {
      const float4 bv = LD4(b2s + j4 * 4);
      a2[j4 * 4 + 0] = bv.x; a2[j4 * 4 + 1] = bv.y;
      a2[j4 * 4 + 2] = bv.z; a2[j4 * 4 + 3] = bv.w;
    }
    const float* __restrict__ gr = GT + (size_t)n * 64;
#pragma unroll 2
    for (int i = 0; i < 64; i += 4) {
      const float4 g = LD4(gr + i);  // per-lane contiguous 16 B
      const float e0 = fmaxf(
          fmaf(dz, w1s[128 + i], fmaf(dy, w1s[64 + i], fmaf(dx, w1s[i], g.x))),
          0.0f);
      const float e1 = fmaxf(
          fmaf(dz, w1s[129 + i],
               fmaf(dy, w1s[65 + i], fmaf(dx, w1s[i + 1], g.y))),
          0.0f);
      const float e2 = fmaxf(
          fmaf(dz, w1s[130 + i],
               fmaf(dy, w1s[66 + i], fmaf(dx, w1s[i + 2], g.z))),
          0.0f);
      const float e3 = fmaxf(
          fmaf(dz, w1s[131 + i],
               fmaf(dy, w1s[67 + i], fmaf(dx, w1s[i + 3], g.w))),
          0.0f);
      const float* __restrict__ w2r = w2s + i * 64;  // uniform -> broadcast
#pragma unroll
      for (int j4 = 0; j4 < 16; j4++) {
        const float4 wa = LD4(w2r + j4 * 4);
        const float4 wb = LD4(w2r + 64 + j4 * 4);
        const float4 wc = LD4(w2r + 128 + j4 * 4);
        const float4 wd = LD4(w2r + 192 + j4 * 4);
        // per-j order e0,e1,e2,e3 == round-6 FMA16ROW sequence
        a2[j4 * 4 + 0] = fmaf(e0, wa.x, a2[j4 * 4 + 0]);
        a2[j4 * 4 + 1] = fmaf(e0, wa.y, a2[j4 * 4 + 1]);
        a2[j4 * 4 + 2] = fmaf(e0, wa.z, a2[j4 * 4 + 2]);
        a2[j4 * 4 + 3] = fmaf(e0, wa.w, a2[j4 * 4 + 3]);
        a2[j4 * 4 + 0] = fmaf(e1, wb.x, a2[j4 * 4 + 0]);
        a2[j4 * 4 + 1] = fmaf(e1, wb.y, a2[j4 * 4 + 1]);
        a2[j4 * 4 + 2] = fmaf(e1, wb.z, a2[j4 * 4 + 2]);
        a2[j4 * 4 + 3] = fmaf(e1, wb.w, a2[j4 * 4 + 3]);
        a2[j4 * 4 + 0] = fmaf(e2, wc.x, a2[j4 * 4 + 0]);
        a2[j4 * 4 + 1] = fmaf(e2, wc.y, a2[j4 * 4 + 1]);
        a2[j4 * 4 + 2] = fmaf(e2, wc.z, a2[j4 * 4 + 2]);
        a2[j4 * 4 + 3] = fmaf(e2, wc.w, a2[j4 * 4 + 3]);
        a2[j4 * 4 + 0] = fmaf(e3, wd.x, a2[j4 * 4 + 0]);
        a2[j4 * 4 + 1] = fmaf(e3, wd.y, a2[j4 * 4 + 1]);
        a2[j4 * 4 + 2] = fmaf(e3, wd.z, a2[j4 * 4 + 2]);
        a2[j4 * 4 + 3] = fmaf(e3, wd.w, a2[j4 * 4 + 3]);
      }
    }
    // h2 -> LDS once (rotated: bank-conflict-free, same mapping as round 3)
#pragma unroll
    for (int j = 0; j < 64; j++)
      hrow[(j + lane) & 63] = fmaxf(a2[j], 0.0f);

    // ---- L3: 8 groups of 16 channels; h2 read back from LDS ----
#pragma unroll 1
    for (int jg = 0; jg < 8; jg++) {
      vf16 acc;
      SET16(acc, b3s + jg * 16)
      const float* __restrict__ w3g = w3s + jg * 16;  // uniform -> broadcast
#pragma unroll 2
      for (int i = 0; i < 64; i += 4) {
        const float e0 = hrow[(i + 0 + lane) & 63];
        const float e1 = hrow[(i + 1 + lane) & 63];
        const float e2 = hrow[(i + 2 + lane) & 63];
        const float e3 = hrow[(i + 3 + lane) & 63];
        const float* __restrict__ w3r = w3g + i * L3D;
        FMA16ROW(acc, w3r, e0)
        FMA16ROW(acc, w3r + 128, e1)
        FMA16ROW(acc, w3r + 256, e2)
        FMA16ROW(acc, w3r + 384, e3)
      }
#pragma unroll
      for (int t = 0; t < 16; t++) {
        float v = fmaxf(acc[t], 0.0f);
#pragma unroll
        for (int off = 32; off >= 1; off >>= 1)
          v = fmaxf(v, __shfl_xor(v, off, 64));
        if (lane == 0)
          atomicMax((unsigned int*)&out_feat[k * L3D + jg * 16 + t],
                    __float_as_uint(v));
      }
    }
  }
}

// ---------------------------------------------------------------------------
extern "C" void kernel_launch(void* const* d_in, const int* in_sizes, int n_in,
                              void* d_out, int out_size, void* d_ws,
                              size_t ws_size, hipStream_t stream) {
  const float* coords = (const float*)d_in[0];    // [8192,3]
  const float* features = (const float*)d_in[1];  // [8192,64]
  const float* W1 = (const float*)d_in[2];        // [67,64]
  const float* b1 = (const float*)d_in[3];        // [64]
  const float* W2 = (const float*)d_in[4];        // [64,64]
  const float* b2 = (const float*)d_in[5];        // [64]
  const float* W3 = (const float*)d_in[6];        // [64,128]
  const float* b3 = (const float*)d_in[7];        // [128]

  float* out = (float*)d_out;
  float* centers = out;                   // [128*3]
  float* out_feat = out + K_CENTERS * 3;  // [128*128]

  char* ws = (char*)d_ws;
  float* GT = (float*)ws;                            // 2 MB, [8192][64]
  int* Q = (int*)(ws + (size_t)N_POINTS * L1D * 4);  // 2 MB
  int* counts = (int*)(ws + 4 * 1024 * 1024);        // 512 B

  fps_gt_kernel<<<1 + K_CENTERS, FPS_T, 0, stream>>>(
      coords, centers, features, W1, b1, GT, counts, out_feat);
  prep_kernel<<<PREP_PARTS * K_CENTERS, 256, 0, stream>>>(coords, centers,
                                                          counts, Q);
  mlp_kernel<<<MLP_BLOCKS, 256, 0, stream>>>(coords, GT, W1, W2, b2, W3, b3,
                                             centers, counts, Q, out_feat);
}

// Round 6
// 236.335 us; speedup vs baseline: 5.1348x; 1.2488x over previous
//
#include <hip/hip_runtime.h>

#define N_POINTS 8192
#define K_CENTERS 128
#define IFD 64
#define L1D 64
#define L2D 64
#define L3D 128
#define QS 4096  // max points per ball (observed max ~1.7K for N(0,1) coords)

#define LD4(p) (*(const float4*)(p))

// ---------------------------------------------------------------------------
// DPP u64-max step: partner = DPP-permuted (hi,lo); keep the larger key.
// ---------------------------------------------------------------------------
template <int CTRL, int RMASK>
__device__ __forceinline__ void dpp_max_u64(unsigned& hi, unsigned& lo) {
  unsigned h2 = (unsigned)__builtin_amdgcn_update_dpp(
      (int)hi, (int)hi, CTRL, RMASK, 0xF, false);
  unsigned l2 = (unsigned)__builtin_amdgcn_update_dpp(
      (int)lo, (int)lo, CTRL, RMASK, 0xF, false);
  unsigned long long a = ((unsigned long long)hi << 32) | lo;
  unsigned long long b = ((unsigned long long)h2 << 32) | l2;
  if (b > a) { hi = h2; lo = l2; }
}

// ---------------------------------------------------------------------------
// Kernel A: block 0 = FPS (unchanged, ~structural floor); blocks 1..128 =
// GT precompute in natural [n][64] layout + counts/out_feat zeroing.
// ---------------------------------------------------------------------------
#define FPS_T 512
#define FPS_P (N_POINTS / FPS_T)  // 16

#define SMEM_BYTES (98304 + 128)  // fps: 96 KB coords + wmax; GT: 16 KB W

__global__ __launch_bounds__(FPS_T) void fps_gt_kernel(
    const float* __restrict__ coords, float* __restrict__ out_centers,
    const float* __restrict__ features, const float* __restrict__ W1,
    const float* __restrict__ b1, float* __restrict__ GT,
    int* __restrict__ counts, float* __restrict__ out_feat) {
  __shared__ __align__(16) char smem[SMEM_BYTES];
  const int tid = threadIdx.x;

  if (blockIdx.x != 0) {
    // ---- GT precompute (feature half of L1), natural [n][64] layout ----
    float* w = (float*)smem;  // 16 KB
    const int bk = blockIdx.x - 1;
    if (bk == 0 && tid < K_CENTERS) counts[tid] = 0;
    if (bk == 1) {
#pragma unroll 1
      for (int s = tid; s < K_CENTERS * L3D; s += FPS_T) out_feat[s] = 0.0f;
    }
    const int n0 = bk * 64;
    for (int s = tid; s < IFD * L1D; s += FPS_T) w[s] = W1[3 * L1D + s];
    __syncthreads();
    const int j = tid & 63;
    const int nl = tid >> 6;  // 0..7 (uniform per wave -> frow is s_load)
    const float bj = b1[j];
#pragma unroll 1
    for (int itn = 0; itn < 8; itn++) {
      const int nn = nl + itn * 8;  // 0..63
      const float* __restrict__ frow = features + (size_t)(n0 + nn) * IFD;
      float acc = bj;
#pragma unroll 16
      for (int i = 0; i < IFD; i++) acc = fmaf(frow[i], w[i * 64 + j], acc);
      GT[(size_t)(n0 + nn) * 64 + j] = acc;  // coalesced: lane = channel j
    }
    return;
  }

  // ---- FPS (block 0, single CU) — unchanged ----
  float* clds = (float*)smem;  // [8192][3] mirror of coords
  unsigned long long* wmax = (unsigned long long*)(smem + 98304);  // [2][8]
  const int lane = tid & 63;
  const int wid = tid >> 6;

  {
    const float4* __restrict__ src = (const float4*)coords;
    float4* dst = (float4*)smem;
#pragma unroll
    for (int i = 0; i < 12; i++) dst[tid + i * FPS_T] = src[tid + i * FPS_T];
  }

  float px[FPS_P], py[FPS_P], pz[FPS_P], mind[FPS_P];
#pragma unroll
  for (int i = 0; i < FPS_P; i++) {
    int n = tid + i * FPS_T;
    px[i] = coords[3 * n];
    py[i] = coords[3 * n + 1];
    pz[i] = coords[3 * n + 2];
    mind[i] = 1e10f;
  }

  float cx = coords[0], cy = coords[1], cz = coords[2];
  if (tid == 0) {
    out_centers[0] = cx; out_centers[1] = cy; out_centers[2] = cz;
  }
  __syncthreads();  // LDS coords mirror complete

  for (int it = 1; it < K_CENTERS; it++) {
#pragma unroll
    for (int i = 0; i < FPS_P; i++) {
      float dx = px[i] - cx, dy = py[i] - cy, dz = pz[i] - cz;
      float d2 = dx * dx + dy * dy + dz * dz;  // exact expr of passing rounds
      mind[i] = fminf(mind[i], d2);
    }
    // value: depth-4 fmax tree
    float t8[8];
#pragma unroll
    for (int i = 0; i < 8; i++) t8[i] = fmaxf(mind[i], mind[i + 8]);
#pragma unroll
    for (int i = 0; i < 4; i++) t8[i] = fmaxf(t8[i], t8[i + 4]);
    const float bm = fmaxf(fmaxf(t8[0], t8[1]), fmaxf(t8[2], t8[3]));
    // index: 16 parallel cndmask + depth-4 min tree (first match = min idx)
    int cand[FPS_P];
#pragma unroll
    for (int i = 0; i < FPS_P; i++)
      cand[i] = (mind[i] == bm) ? (tid + i * FPS_T) : 0x7FFFFFFF;
#pragma unroll
    for (int s = 8; s > 0; s >>= 1)
#pragma unroll
      for (int i = 0; i < s; i++) cand[i] = min(cand[i], cand[i + s]);

    unsigned hi = __float_as_uint(bm);                  // bm >= 0
    unsigned lo = (unsigned)(N_POINTS - 1 - cand[0]);   // max -> min index
    dpp_max_u64<0xB1, 0xF>(hi, lo);   // quad_perm [1,0,3,2]  (xor 1)
    dpp_max_u64<0x4E, 0xF>(hi, lo);   // quad_perm [2,3,0,1]  (xor 2)
    dpp_max_u64<0x141, 0xF>(hi, lo);  // row_half_mirror      (xor 7)
    dpp_max_u64<0x140, 0xF>(hi, lo);  // row_mirror           (xor 15)
    dpp_max_u64<0x142, 0xA>(hi, lo);  // bcast15 -> rows 1,3
    dpp_max_u64<0x143, 0xC>(hi, lo);  // bcast31 -> rows 2,3; lane63 = max
    const int buf = it & 1;
    if (lane == 63)
      wmax[(buf << 3) + wid] = ((unsigned long long)hi << 32) | lo;
    __syncthreads();  // double-buffered: one barrier per iteration is safe

    const unsigned long long* __restrict__ wb = wmax + (buf << 3);
    unsigned long long a0 = wb[0], a1 = wb[1], a2 = wb[2], a3 = wb[3];
    unsigned long long a4 = wb[4], a5 = wb[5], a6 = wb[6], a7 = wb[7];
    a0 = a0 > a4 ? a0 : a4;
    a1 = a1 > a5 ? a1 : a5;
    a2 = a2 > a6 ? a2 : a6;
    a3 = a3 > a7 ? a3 : a7;
    a0 = a0 > a2 ? a0 : a2;
    a1 = a1 > a3 ? a1 : a3;
    a0 = a0 > a1 ? a0 : a1;
    const int widx = N_POINTS - 1 - (int)(a0 & 0xFFFFFFFFull);
    cx = clds[widx * 3];          // broadcast ds_read, no barrier needed
    cy = clds[widx * 3 + 1];
    cz = clds[widx * 3 + 2];
    if (tid == 0) {
      out_centers[3 * it] = cx;
      out_centers[3 * it + 1] = cy;
      out_centers[3 * it + 2] = cz;
    }
  }
}

// ---------------------------------------------------------------------------
// Kernel B: ball query, 512 blocks, global atomic slot alloc. Unchanged.
// ---------------------------------------------------------------------------
#define PREP_PARTS 4
#define PREP_PTS (N_POINTS / PREP_PARTS)  // 2048

__global__ __launch_bounds__(256) void prep_kernel(
    const float* __restrict__ coords, const float* __restrict__ centers,
    int* __restrict__ counts, int* __restrict__ Q) {
  const int tid = threadIdx.x;
  const int k = blockIdx.x >> 2;
  const int part = blockIdx.x & 3;
  const float cx = centers[3 * k], cy = centers[3 * k + 1],
              cz = centers[3 * k + 2];
  const int nbase = part * PREP_PTS;
#pragma unroll
  for (int s = 0; s < PREP_PTS / 256; s++) {
    const int n = nbase + s * 256 + tid;
    float dx = coords[3 * n] - cx;
    float dy = coords[3 * n + 1] - cy;
    float dz = coords[3 * n + 2] - cz;
    float d2 = dx * dx + dy * dy + dz * dz;
    if (sqrtf(d2) < 1.0f) {  // match reference: norm(rel) < RADIUS
      int p = atomicAdd(&counts[k], 1);  // wave-coalesced by compiler
      if (p < QS) Q[(k << 12) + p] = n;  // consecutive p -> coalesced store
    }
  }
}

// ---------------------------------------------------------------------------
// Kernel C (round-13): BLOCK-COOPERATIVE chunks. Post-mortem r3/r5: mlp is
// latency-bound (VALUBusy ~6%), time ~ 1/(waves/SIMD); the hbuf layout
// (256 B LDS/thread) caps occupancy at ~2 waves/SIMD, and per-lane GT row
// reads are 64-line gathers. New structure:
//  - block (4 waves) processes one 64-pt chunk; GT rows staged COALESCED
//    into a [64][65] LDS tile (pad 65 -> 2-way bank alias = free),
//  - thread (p=lane, g=wave): L1+L2 -> 16 h2 channels in regs; h2 written
//    back into the same tile (barrier-separated reuse); L3 -> 32 channels,
//    running max in regs, flushed per center via shfl + atomicMax,
//  - weights via SCALAR path: gu = readfirstlane(wid) makes all weight
//    addresses provably uniform -> s_load + FMA-with-SGPR. No weight LDS.
//  - LDS ~18 KB, __launch_bounds__(256,4) -> 4 blocks/CU = 4 waves/SIMD.
// Per-channel FMA order (b-init, i ascending) identical -> bit-identical.
// ---------------------------------------------------------------------------
#define MLP_BLOCKS 1024

__global__ __launch_bounds__(256, 4) void mlp_kernel(
    const float* __restrict__ coords, const float* __restrict__ GT,
    const float* __restrict__ W1, const float* __restrict__ W2,
    const float* __restrict__ b2, const float* __restrict__ W3,
    const float* __restrict__ b3, const float* __restrict__ centers,
    const int* __restrict__ counts, const int* __restrict__ Q,
    float* __restrict__ out_feat) {
  __shared__ float gt2[64 * 65];   // 16.64 KB: GT chunk tile, reused for h2
  __shared__ float cst[3 * 64 + 64 + 128];  // W1 coord rows + b2 + b3
  const int tid = threadIdx.x;
  const int lane = tid & 63;
  const int wid = tid >> 6;
  const int gu = __builtin_amdgcn_readfirstlane(wid);  // uniform wave id

  for (int s = tid; s < 384; s += 256) {
    float v;
    if (s < 192) v = W1[s];
    else if (s < 256) v = b2[s - 192];
    else v = b3[s - 256];
    cst[s] = v;
  }

  // per-wave chunk prefix over centers: P_k = ceil(min(counts[k],QS)/64)
  int c0c = counts[lane];      if (c0c > QS) c0c = QS;
  int c1c = counts[64 + lane]; if (c1c > QS) c1c = QS;
  int s0 = (c0c + 63) >> 6;
  int s1 = (c1c + 63) >> 6;
#pragma unroll
  for (int off = 1; off < 64; off <<= 1) {
    int t0 = __shfl_up(s0, off, 64);
    int t1 = __shfl_up(s1, off, 64);
    if (lane >= off) { s0 += t0; s1 += t1; }
  }
  s1 += __shfl(s0, 63, 64);
  const int C = __shfl(s1, 63, 64);  // total chunks
  const int p1 = s0;                 // prefix[lane+1]
  const int p65 = s1;                // prefix[lane+65]

  // contiguous chunk range per block (minimizes per-center flushes)
  const int cpb = (C + MLP_BLOCKS - 1) / MLP_BLOCKS;
  const int cbeg = blockIdx.x * cpb;
  const int cend = min(cbeg + cpb, C);
  __syncthreads();  // cst ready
  if (cbeg >= C) return;

  float vmax[32];
#pragma unroll
  for (int t = 0; t < 32; t++) vmax[t] = 0.0f;
  int kprev = -1;

  for (int c = cbeg; c < cend; c++) {
    int k = __popcll(__ballot(p1 <= c)) + __popcll(__ballot(p65 <= c));
    k = __builtin_amdgcn_readfirstlane(k);
    int pk = 0;
    if (k > 0)
      pk = (k <= 64) ? __shfl(s0, k - 1, 64) : __shfl(s1, k - 65, 64);
    int Mk = counts[k];
    if (Mk > QS) Mk = QS;
    const int m0 = (c - pk) * 64;
    const int base = (k << 12) + m0;
    const int mcap = Mk - 1 - m0;  // >= 0 (chunk exists)

    if (k != kprev) {
      if (kprev >= 0) {
        // flush previous center
#pragma unroll
        for (int t = 0; t < 32; t++) {
          float v = vmax[t];
#pragma unroll
          for (int off = 32; off >= 1; off >>= 1)
            v = fmaxf(v, __shfl_xor(v, off, 64));
          if (lane == 0)
            atomicMax((unsigned int*)&out_feat[kprev * L3D + gu * 32 + t],
                      __float_as_uint(v));
          vmax[t] = 0.0f;
        }
      }
      kprev = k;
    }

    // ---- stage 16 GT rows per wave, coalesced (lane = channel) ----
#pragma unroll 4
    for (int it = 0; it < 16; it++) {
      int row = (gu << 4) + it;
      int rr = row < mcap ? row : mcap;  // clamp -> duplicate pad (max-safe)
      int nrow = Q[base + rr];           // wave-uniform address
      nrow = __builtin_amdgcn_readfirstlane(nrow);
      gt2[row * 65 + lane] = GT[(size_t)nrow * 64 + lane];
    }
    __syncthreads();

    // ---- L1+L2: thread (p=lane, g=wave) -> 16 h2 channels ----
    int m = m0 + lane;
    if (m >= Mk) m = Mk - 1;
    const int n = Q[(k << 12) + m];
    const float cx = centers[3 * k], cy = centers[3 * k + 1],
                cz = centers[3 * k + 2];
    const float dx = coords[3 * n] - cx;
    const float dy = coords[3 * n + 1] - cy;
    const float dz = coords[3 * n + 2] - cz;

    float acc[16];
#pragma unroll
    for (int t = 0; t < 16; t++) acc[t] = cst[192 + gu * 16 + t];
    const float* __restrict__ w2u = W2 + gu * 16;  // uniform -> s_load path
#pragma unroll 4
    for (int i = 0; i < 64; i++) {
      const float g = gt2[lane * 65 + i];  // 2-way bank alias: free
      const float e = fmaxf(
          fmaf(dz, cst[128 + i], fmaf(dy, cst[64 + i], fmaf(dx, cst[i], g))),
          0.0f);
      const float* __restrict__ wr = w2u + i * 64;
#pragma unroll
      for (int t = 0; t < 16; t += 4) {
        const float4 w = LD4(wr + t);
        acc[t + 0] = fmaf(e, w.x, acc[t + 0]);
        acc[t + 1] = fmaf(e, w.y, acc[t + 1]);
        acc[t + 2] = fmaf(e, w.z, acc[t + 2]);
        acc[t + 3] = fmaf(e, w.w, acc[t + 3]);
      }
    }
    __syncthreads();  // all gt2 reads done before h2 overwrite

    // ---- h2 (relu) back into the tile: row p, cols [gu*16, gu*16+16) ----
#pragma unroll
    for (int t = 0; t < 16; t++)
      gt2[lane * 65 + gu * 16 + t] = fmaxf(acc[t], 0.0f);
    __syncthreads();

    // ---- L3: thread (p=lane, g=wave) -> 32 channels, running max ----
    float a3[32];
#pragma unroll
    for (int t = 0; t < 32; t++) a3[t] = cst[256 + gu * 32 + t];
    const float* __restrict__ w3u = W3 + gu * 32;  // uniform -> s_load path
#pragma unroll 2
    for (int i = 0; i < 64; i++) {
      const float hv = gt2[lane * 65 + i];
      const float* __restrict__ wr = w3u + i * L3D;
#pragma unroll
      for (int t = 0; t < 32; t += 4) {
        const float4 w = LD4(wr + t);
        a3[t + 0] = fmaf(hv, w.x, a3[t + 0]);
        a3[t + 1] = fmaf(hv, w.y, a3[t + 1]);
        a3[t + 2] = fmaf(hv, w.z, a3[t + 2]);
        a3[t + 3] = fmaf(hv, w.w, a3[t + 3]);
      }
    }
#pragma unroll
    for (int t = 0; t < 32; t++)
      vmax[t] = fmaxf(vmax[t], fmaxf(a3[t], 0.0f));
    __syncthreads();  // L3 reads done before next chunk's staging
  }

  // final flush
#pragma unroll
  for (int t = 0; t < 32; t++) {
    float v = vmax[t];
#pragma unroll
    for (int off = 32; off >= 1; off >>= 1)
      v = fmaxf(v, __shfl_xor(v, off, 64));
    if (lane == 0)
      atomicMax((unsigned int*)&out_feat[kprev * L3D + gu * 32 + t],
                __float_as_uint(v));
  }
}

// ---------------------------------------------------------------------------
extern "C" void kernel_launch(void* const* d_in, const int* in_sizes, int n_in,
                              void* d_out, int out_size, void* d_ws,
                              size_t ws_size, hipStream_t stream) {
  const float* coords = (const float*)d_in[0];    // [8192,3]
  const float* features = (const float*)d_in[1];  // [8192,64]
  const float* W1 = (const float*)d_in[2];        // [67,64]
  const float* b1 = (const float*)d_in[3];        // [64]
  const float* W2 = (const float*)d_in[4];        // [64,64]
  const float* b2 = (const float*)d_in[5];        // [64]
  const float* W3 = (const float*)d_in[6];        // [64,128]
  const float* b3 = (const float*)d_in[7];        // [128]

  float* out = (float*)d_out;
  float* centers = out;                   // [128*3]
  float* out_feat = out + K_CENTERS * 3;  // [128*128]

  char* ws = (char*)d_ws;
  float* GT = (float*)ws;                            // 2 MB, [8192][64]
  int* Q = (int*)(ws + (size_t)N_POINTS * L1D * 4);  // 2 MB
  int* counts = (int*)(ws + 4 * 1024 * 1024);        // 512 B

  fps_gt_kernel<<<1 + K_CENTERS, FPS_T, 0, stream>>>(
      coords, centers, features, W1, b1, GT, counts, out_feat);
  prep_kernel<<<PREP_PARTS * K_CENTERS, 256, 0, stream>>>(coords, centers,
                                                          counts, Q);
  mlp_kernel<<<MLP_BLOCKS, 256, 0, stream>>>(coords, GT, W1, W2, b2, W3, b3,
                                             centers, counts, Q, out_feat);
}